// Round 1
// baseline (170.963 us; speedup 1.0000x reference)
//
#include <hip/hip_runtime.h>
#include <math.h>

// Problem constants (fixed by setup_inputs: [16,1,1024,1024] fp32)
constexpr int IMG_B = 16;
constexpr int IMG_H = 1024;
constexpr int IMG_W = 1024;
constexpr int ROWS_PER_THREAD = 8;
constexpr int BLOCK = 256;               // 256 threads = 256 consecutive columns
constexpr int BX_TILES = IMG_W / BLOCK;              // 4
constexpr int BY_TILES = IMG_H / ROWS_PER_THREAD;    // 128
constexpr int NBLOCKS  = IMG_B * BY_TILES * BX_TILES; // 8192
constexpr float EPS = 1e-8f;

// curvature of one 3x3 window; a_rc = dem[y-1+r][x-1+c] (zero-padded OOB)
// XLA conv_general_dilated is cross-correlation: out[y,x] = sum K[r][c]*in[y+r-1,x+c-1]
__device__ __forceinline__ void curv3(
    float a00, float a01, float a02,
    float a10, float a11, float a12,
    float a20, float a21, float a22,
    float& prof, float& plan, float& mean)
{
    // sobel_x (pre /8): t1 + 2*t3 + t2
    const float t1 = a02 - a00;
    const float t2 = a22 - a20;
    const float t3 = a12 - a10;
    const float gx = (t1 + t2) + 2.0f * t3;
    // sobel_y (pre /8)
    const float t4 = a20 - a00;
    const float t5 = a22 - a02;
    const float t6 = a21 - a01;
    const float gy = (t4 + t5) + 2.0f * t6;
    // k_xx*3 = total - 3*c1 ; k_yy*3 = total - 3*r1 ; k_xy*4 = t1 - t2
    const float r0 = a00 + a01 + a02;
    const float r1 = a10 + a11 + a12;
    const float r2 = a20 + a21 + a22;
    const float tot = (r0 + r2) + r1;
    const float c1 = (a01 + a21) + a11;
    const float rxx = tot - 3.0f * c1;
    const float tyy = tot - 3.0f * r1;
    const float sxy = t1 - t2;

    // fold scales: p=gx/(8*10), r=rxx/(3*100), s=sxy/(4*100)
    const float p = gx * (1.0f / 80.0f);
    const float q = gy * (1.0f / 80.0f);
    const float r = rxx * (1.0f / 300.0f);
    const float s = sxy * (1.0f / 400.0f);
    const float t = tyy * (1.0f / 300.0f);

    const float p2 = p * p, q2 = q * q, pq = p * q;
    const float d1 = p2 + q2;
    const float od = 1.0f + d1;
    const float sq_od = __builtin_amdgcn_sqrtf(od);   // v_sqrt_f32
    const float sq_d  = __builtin_amdgcn_sqrtf(d1);
    const float s2pq = 2.0f * s * pq;
    const float nprof = (r * p2 + s2pq) + t * q2;
    const float nplan = (r * q2 - s2pq) + t * p2;
    const float nmean = ((1.0f + q2) * r - 2.0f * pq * s) + (1.0f + p2) * t;

    prof = nprof * __builtin_amdgcn_rcpf(d1 * sq_od + EPS); // v_rcp_f32
    plan = nplan * __builtin_amdgcn_rcpf(d1 * sq_d + EPS);
    mean = nmean * __builtin_amdgcn_rcpf(2.0f * od * sq_od + EPS);
    if (d1 < EPS) { prof = 0.0f; plan = 0.0f; }
}

__global__ __launch_bounds__(BLOCK) void curv_loss_main(
    const float* __restrict__ pred, const float* __restrict__ targ,
    float* __restrict__ blocksums)
{
    const int tid = threadIdx.x;
    int b = blockIdx.x;
    const int bx  = b & (BX_TILES - 1);
    const int by  = (b >> 2) & (BY_TILES - 1);
    const int img = b >> 9;                 // 4*128 = 512 blocks per image
    const int x  = bx * BLOCK + tid;
    const int y0 = by * ROWS_PER_THREAD;
    const size_t base = (size_t)img * (size_t)(IMG_H * IMG_W);
    const float* __restrict__ P = pred + base;
    const float* __restrict__ T = targ + base;
    const bool xm_ok = (x > 0);
    const bool xp_ok = (x < IMG_W - 1);

    auto loadrow = [&](const float* __restrict__ A, int y,
                       float& c0, float& c1, float& c2) {
        if ((unsigned)y < (unsigned)IMG_H) {
            const int o = y * IMG_W + x;
            c1 = A[o];
            c0 = xm_ok ? A[o - 1] : 0.0f;
            c2 = xp_ok ? A[o + 1] : 0.0f;
        } else {
            c0 = 0.0f; c1 = 0.0f; c2 = 0.0f;
        }
    };

    // rolling 3-row window for pred (p*) and target (t*): a=y-1, b=y, c=y+1
    float pa0, pa1, pa2, pb0, pb1, pb2, pc0, pc1, pc2;
    float ta0, ta1, ta2, tb0, tb1, tb2, tc0, tc1, tc2;
    loadrow(P, y0 - 1, pa0, pa1, pa2);
    loadrow(T, y0 - 1, ta0, ta1, ta2);
    loadrow(P, y0,     pb0, pb1, pb2);
    loadrow(T, y0,     tb0, tb1, tb2);

    float acc = 0.0f;
#pragma unroll
    for (int i = 0; i < ROWS_PER_THREAD; ++i) {
        loadrow(P, y0 + i + 1, pc0, pc1, pc2);
        loadrow(T, y0 + i + 1, tc0, tc1, tc2);
        float pp, pl, pm, qp, ql, qm;
        curv3(pa0, pa1, pa2, pb0, pb1, pb2, pc0, pc1, pc2, pp, pl, pm);
        curv3(ta0, ta1, ta2, tb0, tb1, tb2, tc0, tc1, tc2, qp, ql, qm);
        acc += 0.5f * fabsf(pp - qp) + 0.3f * fabsf(pl - ql) + 0.2f * fabsf(pm - qm);
        pa0 = pb0; pa1 = pb1; pa2 = pb2;
        pb0 = pc0; pb1 = pc1; pb2 = pc2;
        ta0 = tb0; ta1 = tb1; ta2 = tb2;
        tb0 = tc0; tb1 = tc1; tb2 = tc2;
    }

    // wave64 reduce then cross-wave via LDS
    for (int off = 32; off > 0; off >>= 1) acc += __shfl_down(acc, off, 64);
    __shared__ float ws[BLOCK / 64];
    const int lane = tid & 63, wid = tid >> 6;
    if (lane == 0) ws[wid] = acc;
    __syncthreads();
    if (tid == 0)
        blocksums[blockIdx.x] = (ws[0] + ws[1]) + (ws[2] + ws[3]);
}

__global__ __launch_bounds__(BLOCK) void curv_loss_final(
    const float* __restrict__ blocksums, float* __restrict__ out)
{
    const int tid = threadIdx.x;
    float v = 0.0f;
    for (int i = tid; i < NBLOCKS; i += BLOCK) v += blocksums[i];
    for (int off = 32; off > 0; off >>= 1) v += __shfl_down(v, off, 64);
    __shared__ float ws[BLOCK / 64];
    const int lane = tid & 63, wid = tid >> 6;
    if (lane == 0) ws[wid] = v;
    __syncthreads();
    if (tid == 0) {
        const float tot = (ws[0] + ws[1]) + (ws[2] + ws[3]);
        out[0] = tot * (1.0f / (float)(IMG_B * IMG_H * IMG_W));
    }
}

extern "C" void kernel_launch(void* const* d_in, const int* in_sizes, int n_in,
                              void* d_out, int out_size, void* d_ws, size_t ws_size,
                              hipStream_t stream)
{
    const float* pred = (const float*)d_in[0];
    const float* targ = (const float*)d_in[1];
    float* out = (float*)d_out;
    float* blocksums = (float*)d_ws;   // NBLOCKS floats = 32 KiB; every slot written each call

    curv_loss_main<<<NBLOCKS, BLOCK, 0, stream>>>(pred, targ, blocksums);
    curv_loss_final<<<1, BLOCK, 0, stream>>>(blocksums, out);
}